// Round 1
// baseline (90.466 us; speedup 1.0000x reference)
//
#include <hip/hip_runtime.h>
#include <hip/hip_fp16.h>

#define HH 512
#define WW 512
#define BB 4
#define CC 21
#define TS 16
#define HS 20   // TS + 2*PADR
#define PADR 2

typedef _Float16 h2 __attribute__((ext_vector_type(2)));

__device__ __forceinline__ int refl(int i, int n) {
    if (i < 0) i = -i;
    if (i >= n) i = 2 * n - 2 - i;
    return i;
}

__device__ __forceinline__ float dot2(unsigned int a, unsigned int b, float c) {
#if __has_builtin(__builtin_amdgcn_fdot2)
    return __builtin_amdgcn_fdot2(__builtin_bit_cast(h2, a), __builtin_bit_cast(h2, b), c, false);
#else
    h2 ha = __builtin_bit_cast(h2, a), hb = __builtin_bit_cast(h2, b);
    return c + (float)ha[0] * (float)hb[0] + (float)ha[1] * (float)hb[1];
#endif
}

__global__ void zero_kernel(float* o) { *o = 0.0f; }

__global__ __launch_bounds__(256) void lnc_kernel(const float* __restrict__ preds,
                                                  const float* __restrict__ images,
                                                  float* __restrict__ out) {
    // probs as fp16 pairs: 3 planes of uint4 (8 halves each) = 24 channels (21 + 3 zero pad)
    __shared__ uint4 sP[3][HS * HS];
    // (r, g, b, S2) per halo pixel
    __shared__ float4 sI[HS * HS];
    __shared__ float sRed[4];

    const int b = blockIdx.z;
    const int bx0 = blockIdx.x * TS;
    const int by0 = blockIdx.y * TS;
    const int t = threadIdx.x;

    // ---- stage halo: gather preds channels, softmax in regs, pack fp16 -> LDS ----
    for (int h = t; h < HS * HS; h += 256) {
        const int hy = h / HS, hx = h - hy * HS;
        const int gy = refl(by0 + hy - PADR, HH);
        const int gx = refl(bx0 + hx - PADR, WW);
        const float* pb = preds + (size_t)b * CC * HH * WW + (size_t)gy * WW + gx;
        float v[CC];
        float m = -1e30f;
#pragma unroll
        for (int c = 0; c < CC; ++c) {
            v[c] = pb[(size_t)c * (HH * WW)];
            m = fmaxf(m, v[c]);
        }
        float s = 0.0f;
#pragma unroll
        for (int c = 0; c < CC; ++c) {
            v[c] = __expf(v[c] - m);
            s += v[c];
        }
        const float inv = 1.0f / s;
        float s2 = 0.0f;
        unsigned int w[12];
#pragma unroll
        for (int k = 0; k < 12; ++k) {
            const float p0 = (2 * k < CC) ? v[2 * k] * inv : 0.0f;
            const float p1 = (2 * k + 1 < CC) ? v[2 * k + 1] * inv : 0.0f;
            const _Float16 q0 = (_Float16)p0, q1 = (_Float16)p1;
            const float f0 = (float)q0, f1 = (float)q1;
            s2 += f0 * f0 + f1 * f1;  // S2 from rounded values -> exact cancellation vs dot
            const unsigned short u0 = __builtin_bit_cast(unsigned short, q0);
            const unsigned short u1 = __builtin_bit_cast(unsigned short, q1);
            w[k] = (unsigned int)u0 | ((unsigned int)u1 << 16);
        }
        sP[0][h] = make_uint4(w[0], w[1], w[2], w[3]);
        sP[1][h] = make_uint4(w[4], w[5], w[6], w[7]);
        sP[2][h] = make_uint4(w[8], w[9], w[10], w[11]);
        const float* ib = images + (size_t)b * 3 * HH * WW + (size_t)gy * WW + gx;
        float4 im;
        im.x = ib[0];
        im.y = ib[(size_t)(HH * WW)];
        im.z = ib[(size_t)(2 * HH * WW)];
        im.w = s2;
        sI[h] = im;
    }
    __syncthreads();

    // ---- main: each thread owns one inner pixel ----
    const int tx = t & (TS - 1);
    const int ty = t >> 4;
    const int base = (ty + PADR) * HS + (tx + PADR);
    const uint4 a0 = sP[0][base];
    const uint4 a1 = sP[1][base];
    const uint4 a2 = sP[2][base];
    const float4 ai = sI[base];

    float acc = 0.0f;
#pragma unroll
    for (int dy = -2; dy <= 2; ++dy) {
#pragma unroll
        for (int dx = -2; dx <= 2; ++dx) {
            if (dy == 0 && dx == 0) continue;
            const int nb = base + dy * HS + dx;
            const uint4 q0 = sP[0][nb];
            const uint4 q1 = sP[1][nb];
            const uint4 q2 = sP[2][nb];
            const float4 qi = sI[nb];
            float d = 0.0f;
            d = dot2(a0.x, q0.x, d); d = dot2(a0.y, q0.y, d);
            d = dot2(a0.z, q0.z, d); d = dot2(a0.w, q0.w, d);
            d = dot2(a1.x, q1.x, d); d = dot2(a1.y, q1.y, d);
            d = dot2(a1.z, q1.z, d); d = dot2(a1.w, q1.w, d);
            d = dot2(a2.x, q2.x, d); d = dot2(a2.y, q2.y, d);
            d = dot2(a2.z, q2.z, d); d = dot2(a2.w, q2.w, d);
            const float dr = ai.x - qi.x;
            const float dg = ai.y - qi.y;
            const float db = ai.z - qi.z;
            const float cd = dr * dr + dg * dg + db * db;
            const float aff = __expf(-200.0f * cd);
            const float ssd = ai.w + qi.w - 2.0f * d;
            acc += aff * ssd;
        }
    }

    // ---- reduce: wave shuffle -> LDS -> one atomic per block ----
#pragma unroll
    for (int o = 32; o >= 1; o >>= 1) acc += __shfl_xor(acc, o, 64);
    if ((t & 63) == 0) sRed[t >> 6] = acc;
    __syncthreads();
    if (t == 0) {
        constexpr float SCALE = (float)(1.0 / (504.0 * 1048576.0));
        atomicAdd(out, (sRed[0] + sRed[1] + sRed[2] + sRed[3]) * SCALE);
    }
}

extern "C" void kernel_launch(void* const* d_in, const int* in_sizes, int n_in,
                              void* d_out, int out_size, void* d_ws, size_t ws_size,
                              hipStream_t stream) {
    const float* preds = (const float*)d_in[0];
    const float* images = (const float*)d_in[1];
    float* out = (float*)d_out;
    zero_kernel<<<1, 1, 0, stream>>>(out);
    dim3 grid(WW / TS, HH / TS, BB);
    lnc_kernel<<<grid, 256, 0, stream>>>(preds, images, out);
}

// Round 2
// 88.385 us; speedup vs baseline: 1.0235x; 1.0235x over previous
//
#include <hip/hip_runtime.h>
#include <hip/hip_fp16.h>

#define HH 512
#define WW 512
#define BB 4
#define CC 21
#define TS 16
#define HSY 18   // TS + 2  (only dy = 0..+2 needed under symmetry)
#define HSX 20   // TS + 4  (dx = -2..+2)
#define PADX 2

typedef _Float16 h2 __attribute__((ext_vector_type(2)));

__device__ __forceinline__ int refl(int i, int n) {
    if (i < 0) i = -i;
    if (i >= n) i = 2 * n - 2 - i;
    return i;
}

__device__ __forceinline__ float dot2(unsigned int a, unsigned int b, float c) {
#if __has_builtin(__builtin_amdgcn_fdot2)
    return __builtin_amdgcn_fdot2(__builtin_bit_cast(h2, a), __builtin_bit_cast(h2, b), c, false);
#else
    h2 ha = __builtin_bit_cast(h2, a), hb = __builtin_bit_cast(h2, b);
    return c + (float)ha[0] * (float)hb[0] + (float)ha[1] * (float)hb[1];
#endif
}

__global__ void zero_kernel(float* o) { *o = 0.0f; }

__global__ __launch_bounds__(256) void lnc_kernel(const float* __restrict__ preds,
                                                  const float* __restrict__ images,
                                                  float* __restrict__ out) {
    // probs as fp16 pairs: 3 planes of uint4 (8 halves each) = 24 channels (21 + 3 zero pad)
    __shared__ uint4 sP[3][HSY * HSX];
    // (r, g, b, S2) per halo pixel
    __shared__ float4 sI[HSY * HSX];
    __shared__ float sRed[4];

    const int b = blockIdx.z;
    const int bx0 = blockIdx.x * TS;
    const int by0 = blockIdx.y * TS;
    const int t = threadIdx.x;

    // ---- stage halo: gather preds channels, softmax in regs, pack fp16 -> LDS ----
    for (int h = t; h < HSY * HSX; h += 256) {
        const int hy = h / HSX, hx = h - hy * HSX;
        const int gy = refl(by0 + hy, HH);          // rows y0 .. y0+17
        const int gx = refl(bx0 + hx - PADX, WW);   // cols x0-2 .. x0+17
        const float* pb = preds + (size_t)b * CC * HH * WW + (size_t)gy * WW + gx;
        float v[CC];
        float m = -1e30f;
#pragma unroll
        for (int c = 0; c < CC; ++c) {
            v[c] = pb[(size_t)c * (HH * WW)];
            m = fmaxf(m, v[c]);
        }
        float s = 0.0f;
#pragma unroll
        for (int c = 0; c < CC; ++c) {
            v[c] = __expf(v[c] - m);
            s += v[c];
        }
        const float inv = 1.0f / s;
        float s2 = 0.0f;
        unsigned int w[12];
#pragma unroll
        for (int k = 0; k < 12; ++k) {
            const float p0 = (2 * k < CC) ? v[2 * k] * inv : 0.0f;
            const float p1 = (2 * k + 1 < CC) ? v[2 * k + 1] * inv : 0.0f;
            const _Float16 q0 = (_Float16)p0, q1 = (_Float16)p1;
            const float f0 = (float)q0, f1 = (float)q1;
            s2 += f0 * f0 + f1 * f1;  // S2 from rounded values -> exact cancellation vs dot
            const unsigned short u0 = __builtin_bit_cast(unsigned short, q0);
            const unsigned short u1 = __builtin_bit_cast(unsigned short, q1);
            w[k] = (unsigned int)u0 | ((unsigned int)u1 << 16);
        }
        sP[0][h] = make_uint4(w[0], w[1], w[2], w[3]);
        sP[1][h] = make_uint4(w[4], w[5], w[6], w[7]);
        sP[2][h] = make_uint4(w[8], w[9], w[10], w[11]);
        const float* ib = images + (size_t)b * 3 * HH * WW + (size_t)gy * WW + gx;
        float4 im;
        im.x = ib[0];
        im.y = ib[(size_t)(HH * WW)];
        im.z = ib[(size_t)(2 * HH * WW)];
        im.w = s2;
        sI[h] = im;
    }
    __syncthreads();

    // ---- main: each thread owns one inner pixel; half-space offsets, weight 2 ----
    const int tx = t & (TS - 1);
    const int ty = t >> 4;
    const int base = ty * HSX + (tx + PADX);
    const uint4 a0 = sP[0][base];
    const uint4 a1 = sP[1][base];
    const uint4 a2 = sP[2][base];
    const float4 ai = sI[base];

    // half-space: (dy>0) or (dy==0 && dx>0)
    const int OFF[12] = {
        0 * HSX + 1, 0 * HSX + 2,
        1 * HSX - 2, 1 * HSX - 1, 1 * HSX + 0, 1 * HSX + 1, 1 * HSX + 2,
        2 * HSX - 2, 2 * HSX - 1, 2 * HSX + 0, 2 * HSX + 1, 2 * HSX + 2};

    float accA = 0.0f, accB = 0.0f;
#pragma unroll
    for (int k = 0; k < 12; ++k) {
        const int nb = base + OFF[k];
        const uint4 q0 = sP[0][nb];
        const uint4 q1 = sP[1][nb];
        const uint4 q2 = sP[2][nb];
        const float4 qi = sI[nb];
        // 4 independent partial dots: chain depth 3 instead of 12
        float d0 = 0.0f, d1 = 0.0f, d2 = 0.0f, d3 = 0.0f;
        d0 = dot2(a0.x, q0.x, d0); d1 = dot2(a0.y, q0.y, d1);
        d2 = dot2(a0.z, q0.z, d2); d3 = dot2(a0.w, q0.w, d3);
        d0 = dot2(a1.x, q1.x, d0); d1 = dot2(a1.y, q1.y, d1);
        d2 = dot2(a1.z, q1.z, d2); d3 = dot2(a1.w, q1.w, d3);
        d0 = dot2(a2.x, q2.x, d0); d1 = dot2(a2.y, q2.y, d1);
        d2 = dot2(a2.z, q2.z, d2); d3 = dot2(a2.w, q2.w, d3);
        const float d = (d0 + d1) + (d2 + d3);
        const float dr = ai.x - qi.x;
        const float dg = ai.y - qi.y;
        const float db = ai.z - qi.z;
        const float cd = dr * dr + dg * dg + db * db;
        const float aff = __expf(-200.0f * cd);
        const float ssd = ai.w + qi.w - 2.0f * d;
        if (k & 1) accB += aff * ssd; else accA += aff * ssd;
    }
    float acc = accA + accB;

    // ---- reduce: wave shuffle -> LDS -> one atomic per block ----
#pragma unroll
    for (int o = 32; o >= 1; o >>= 1) acc += __shfl_xor(acc, o, 64);
    if ((t & 63) == 0) sRed[t >> 6] = acc;
    __syncthreads();
    if (t == 0) {
        // ×2 for the symmetric half-space
        constexpr float SCALE = (float)(2.0 / (504.0 * 1048576.0));
        atomicAdd(out, (sRed[0] + sRed[1] + sRed[2] + sRed[3]) * SCALE);
    }
}

extern "C" void kernel_launch(void* const* d_in, const int* in_sizes, int n_in,
                              void* d_out, int out_size, void* d_ws, size_t ws_size,
                              hipStream_t stream) {
    const float* preds = (const float*)d_in[0];
    const float* images = (const float*)d_in[1];
    float* out = (float*)d_out;
    zero_kernel<<<1, 1, 0, stream>>>(out);
    dim3 grid(WW / TS, HH / TS, BB);
    lnc_kernel<<<grid, 256, 0, stream>>>(preds, images, out);
}

// Round 3
// 45.721 us; speedup vs baseline: 1.9787x; 1.9331x over previous
//
#include <hip/hip_runtime.h>
#include <hip/hip_fp16.h>

#define HH 512
#define WW 512
#define BB 4
#define CC 21
#define TSX 64
#define TSY 8
#define HSY (TSY + 2)   // 10 rows: dy = 0..+2 under half-space symmetry
#define HSX (TSX + 4)   // 68 cols: dx = -2..+2
#define PADX 2
#define NTHR 512
#define NBLK ((WW / TSX) * (HH / TSY) * BB)   // 8*64*4 = 2048

typedef _Float16 h2 __attribute__((ext_vector_type(2)));

__device__ __forceinline__ int refl(int i, int n) {
    if (i < 0) i = -i;
    if (i >= n) i = 2 * n - 2 - i;
    return i;
}

__device__ __forceinline__ float dot2(unsigned int a, unsigned int b, float c) {
#if __has_builtin(__builtin_amdgcn_fdot2)
    return __builtin_amdgcn_fdot2(__builtin_bit_cast(h2, a), __builtin_bit_cast(h2, b), c, false);
#else
    h2 ha = __builtin_bit_cast(h2, a), hb = __builtin_bit_cast(h2, b);
    return c + (float)ha[0] * (float)hb[0] + (float)ha[1] * (float)hb[1];
#endif
}

__global__ void zero_kernel(float* o) { *o = 0.0f; }

__global__ __launch_bounds__(NTHR) void lnc_kernel(const float* __restrict__ preds,
                                                   const float* __restrict__ images,
                                                   float* __restrict__ out) {
    __shared__ uint4 sP[3][HSY * HSX];   // fp16-packed probs, 24 ch (21 + 3 zero pad)
    __shared__ float4 sI[HSY * HSX];     // (r, g, b, S2)
    __shared__ float sRed[NTHR / 64];

    // XCD-aware chunked swizzle: 2048 blocks, 8 XCDs, 256 per XCD (bijective)
    const int id = blockIdx.x;
    const int swz = (id & 7) * (NBLK / 8) + (id >> 3);
    const int b = swz >> 9;               // 512 tiles per image
    const int rem = swz & 511;
    const int tyb = rem >> 3;             // 64 tile-rows
    const int txb = rem & 7;              // 8 tile-cols
    const int bx0 = txb * TSX;
    const int by0 = tyb * TSY;
    const int t = threadIdx.x;

    // ---- stage halo: gather 21 channels, softmax in regs, pack fp16 -> LDS ----
    for (int h = t; h < HSY * HSX; h += NTHR) {
        const int hy = h / HSX, hx = h - hy * HSX;
        const int gy = refl(by0 + hy, HH);          // rows y0 .. y0+9
        const int gx = refl(bx0 + hx - PADX, WW);   // cols x0-2 .. x0+65
        const float* pb = preds + (size_t)b * CC * HH * WW + (size_t)gy * WW + gx;
        float v[CC];
        float m = -1e30f;
#pragma unroll
        for (int c = 0; c < CC; ++c) {
            v[c] = pb[(size_t)c * (HH * WW)];
            m = fmaxf(m, v[c]);
        }
        float s = 0.0f;
#pragma unroll
        for (int c = 0; c < CC; ++c) {
            v[c] = __expf(v[c] - m);
            s += v[c];
        }
        const float inv = 1.0f / s;
        float s2 = 0.0f;
        unsigned int w[12];
#pragma unroll
        for (int k = 0; k < 12; ++k) {
            const float p0 = (2 * k < CC) ? v[2 * k] * inv : 0.0f;
            const float p1 = (2 * k + 1 < CC) ? v[2 * k + 1] * inv : 0.0f;
            const _Float16 q0 = (_Float16)p0, q1 = (_Float16)p1;
            const float f0 = (float)q0, f1 = (float)q1;
            s2 += f0 * f0 + f1 * f1;  // S2 from rounded values -> exact cancellation vs dot
            const unsigned short u0 = __builtin_bit_cast(unsigned short, q0);
            const unsigned short u1 = __builtin_bit_cast(unsigned short, q1);
            w[k] = (unsigned int)u0 | ((unsigned int)u1 << 16);
        }
        sP[0][h] = make_uint4(w[0], w[1], w[2], w[3]);
        sP[1][h] = make_uint4(w[4], w[5], w[6], w[7]);
        sP[2][h] = make_uint4(w[8], w[9], w[10], w[11]);
        const float* ib = images + (size_t)b * 3 * HH * WW + (size_t)gy * WW + gx;
        float4 im;
        im.x = ib[0];
        im.y = ib[(size_t)(HH * WW)];
        im.z = ib[(size_t)(2 * HH * WW)];
        im.w = s2;
        sI[h] = im;
    }
    __syncthreads();

    // ---- main: each thread owns one inner pixel; half-space offsets, weight 2 ----
    const int tx = t & (TSX - 1);
    const int ty = t >> 6;
    const int base = ty * HSX + (tx + PADX);
    const uint4 a0 = sP[0][base];
    const uint4 a1 = sP[1][base];
    const uint4 a2 = sP[2][base];
    const float4 ai = sI[base];

    // half-space: (dy>0) or (dy==0 && dx>0)
    const int OFF[12] = {
        0 * HSX + 1, 0 * HSX + 2,
        1 * HSX - 2, 1 * HSX - 1, 1 * HSX + 0, 1 * HSX + 1, 1 * HSX + 2,
        2 * HSX - 2, 2 * HSX - 1, 2 * HSX + 0, 2 * HSX + 1, 2 * HSX + 2};

    float accA = 0.0f, accB = 0.0f;
#pragma unroll
    for (int k = 0; k < 12; ++k) {
        const int nb = base + OFF[k];
        const uint4 q0 = sP[0][nb];
        const uint4 q1 = sP[1][nb];
        const uint4 q2 = sP[2][nb];
        const float4 qi = sI[nb];
        float d0 = 0.0f, d1 = 0.0f, d2 = 0.0f, d3 = 0.0f;
        d0 = dot2(a0.x, q0.x, d0); d1 = dot2(a0.y, q0.y, d1);
        d2 = dot2(a0.z, q0.z, d2); d3 = dot2(a0.w, q0.w, d3);
        d0 = dot2(a1.x, q1.x, d0); d1 = dot2(a1.y, q1.y, d1);
        d2 = dot2(a1.z, q1.z, d2); d3 = dot2(a1.w, q1.w, d3);
        d0 = dot2(a2.x, q2.x, d0); d1 = dot2(a2.y, q2.y, d1);
        d2 = dot2(a2.z, q2.z, d2); d3 = dot2(a2.w, q2.w, d3);
        const float d = (d0 + d1) + (d2 + d3);
        const float dr = ai.x - qi.x;
        const float dg = ai.y - qi.y;
        const float db = ai.z - qi.z;
        const float cd = dr * dr + dg * dg + db * db;
        const float aff = __expf(-200.0f * cd);
        const float ssd = ai.w + qi.w - 2.0f * d;
        if (k & 1) accB += aff * ssd; else accA += aff * ssd;
    }
    float acc = accA + accB;

    // ---- reduce: wave shuffle -> LDS -> one atomic per block ----
#pragma unroll
    for (int o = 32; o >= 1; o >>= 1) acc += __shfl_xor(acc, o, 64);
    if ((t & 63) == 0) sRed[t >> 6] = acc;
    __syncthreads();
    if (t == 0) {
        float tot = 0.0f;
#pragma unroll
        for (int i = 0; i < NTHR / 64; ++i) tot += sRed[i];
        constexpr float SCALE = (float)(2.0 / (504.0 * 1048576.0));  // x2 symmetry
        atomicAdd(out, tot * SCALE);
    }
}

extern "C" void kernel_launch(void* const* d_in, const int* in_sizes, int n_in,
                              void* d_out, int out_size, void* d_ws, size_t ws_size,
                              hipStream_t stream) {
    const float* preds = (const float*)d_in[0];
    const float* images = (const float*)d_in[1];
    float* out = (float*)d_out;
    zero_kernel<<<1, 1, 0, stream>>>(out);
    lnc_kernel<<<NBLK, NTHR, 0, stream>>>(preds, images, out);
}